// Round 3
// baseline (114.173 us; speedup 1.0000x reference)
//
#include <hip/hip_runtime.h>
#include <math.h>

#define H 2048
#define W 2048
#define K 16
#define P 15
#define WP 2052        // win pitch: W + 4 replicated guard cols (wrapped float4 reads)
#define LP 272         // LDS colsum pitch

typedef float v4 __attribute__((ext_vector_type(4)));
typedef v4 uv4 __attribute__((aligned(4)));   // dword-aligned vector load

// ---- kernel 1: fused 15x15 exclusive box-sum img -> win (separable, LDS) ----
// Also: block (0,0) computes C = (K - patsum/p^2)/(K-1) and int offsets -> ws.
__global__ void geneo_win(const float* __restrict__ img,
                          float* __restrict__ win,
                          const float* __restrict__ patterns,
                          const float* __restrict__ vectors,
                          float* __restrict__ consts,
                          int* __restrict__ offs) {
    __shared__ float cs[32][LP];   // colsum[ii][col], 34 KB
    __shared__ float psum[4];
    int t  = threadIdx.x;
    int c0 = blockIdx.x * 256;
    int r0 = blockIdx.y * 32;

    // --- consts (one block only; cheap: ~4 v4 loads/thread + wave reduce) ---
    if (blockIdx.x == 0 && blockIdx.y == 0) {
        float ps = 0.f;
        #pragma unroll
        for (int q = 0; q < 4; ++q) {
            int idx = t + q * 256;
            if (idx < 900) {                       // 900 v4 = 3600 floats
                v4 v = *(const v4*)&patterns[idx * 4];
                ps += (v.x + v.y) + (v.z + v.w);
            }
        }
        #pragma unroll
        for (int d = 32; d > 0; d >>= 1) ps += __shfl_down(ps, d, 64);
        if ((t & 63) == 0) psum[t >> 6] = ps;
        if (t < 2 * K) offs[t] = (int)floorf(vectors[t]);
        __syncthreads();
        if (t == 0) {
            float total = (psum[0] + psum[1]) + (psum[2] + psum[3]);
            consts[0] = (16.0f - total * (1.0f / 225.0f)) * (1.0f / 15.0f);
        }
    }

    // --- phase A: vertical running sums (rows [i-15, i-1]) into LDS ---
    int col0 = c0 - 16 + t;        // cols [c0-16, c0+240)
    int col1 = c0 + 240 + t;       // t<16: cols [c0+240, c0+256)
    bool ok0 = (col0 >= 0);
    float s0 = 0.f, s1 = 0.f;
    #pragma unroll
    for (int d = 15; d >= 1; --d) {
        int r = r0 - d;
        if (r >= 0) {
            if (ok0) s0 += img[r * W + col0];
            if (t < 16) s1 += img[r * W + col1];
        }
    }
    #pragma unroll
    for (int ii = 0; ii < 32; ++ii) {
        cs[ii][t] = s0;
        if (t < 16) cs[ii][256 + t] = s1;
        int r = r0 + ii;
        if (ok0) s0 += img[r * W + col0];
        if (t < 16) s1 += img[r * W + col1];
        int rr = r - P;
        if (rr >= 0) {
            if (ok0) s0 -= img[rr * W + col0];
            if (t < 16) s1 -= img[rr * W + col1];
        }
    }
    __syncthreads();

    // --- phase B: horizontal 15-tap (cols [j-15, j-1]), 4 outputs/thread/row ---
    int cg = t & 63;               // col group: cols c0+4cg .. +3
    int rs = t >> 6;               // row sub-index
    int b  = 4 * cg + 1;
    #pragma unroll
    for (int ib = 0; ib < 32; ib += 4) {
        int ii = ib + rs;
        const float* row = &cs[ii][0];
        float x0 = 0.f;
        #pragma unroll
        for (int m = 0; m < P; ++m) x0 += row[b + m];
        float x1 = x0 - row[b]     + row[b + 15];
        float x2 = x1 - row[b + 1] + row[b + 16];
        float x3 = x2 - row[b + 2] + row[b + 17];
        v4 r4 = {x0, x1, x2, x3};
        int gi = r0 + ii;
        *(v4*)&win[gi * WP + c0 + 4 * cg] = r4;
        if (blockIdx.x == 0 && cg == 0)            // guard cols 2048..2051 = cols 0..3
            *(v4*)&win[gi * WP + W] = r4;
    }
}

// ---- kernel 2: 16-way circular-shift gather-sum, XCD-banded ----
__global__ void geneo_gather(const float* __restrict__ win,
                             const float* __restrict__ consts,
                             const int* __restrict__ offs,
                             float* __restrict__ out) {
    __shared__ int soy[K], sox[K];
    __shared__ float sC;
    int t = threadIdx.x;
    if (t < K) { soy[t] = offs[t * 2]; sox[t] = offs[t * 2 + 1]; }
    if (t == 0) sC = consts[0];
    __syncthreads();

    // band swizzle: assuming round-robin d%8 XCD assignment, XCD x gets
    // contiguous rows [x*256, x*256+256) -> its win band (~2.1 MB) fits 4 MiB L2
    int d   = blockIdx.x;
    int xcd = d & 7;
    int m   = d >> 3;              // [0, 512)
    int i   = xcd * 256 + (m >> 1);
    int j   = (m & 1) * 1024 + 4 * t;

    const float S = 1.0f / 3375.0f;  // 1/(p^2 (K-1)), data-independent
    v4 acc = {0.f, 0.f, 0.f, 0.f};
    #pragma unroll
    for (int k = 0; k < K; ++k) {
        int ri = (i - soy[k]) & (H - 1);
        int rj = (j - sox[k]) & (W - 1);
        acc += *(const uv4*)&win[ri * WP + rj];   // guard cols make wrap valid
    }
    v4 o = acc * S + sC;
    *(v4*)&out[i * W + j] = o;
}

extern "C" void kernel_launch(void* const* d_in, const int* in_sizes, int n_in,
                              void* d_out, int out_size, void* d_ws, size_t ws_size,
                              hipStream_t stream) {
    const float* x        = (const float*)d_in[0]; // (1,1,H,W)
    const float* patterns = (const float*)d_in[1]; // (K,P,P)
    const float* vectors  = (const float*)d_in[2]; // (K,2)
    float* out = (float*)d_out;

    float* win    = (float*)d_ws;          // H*WP floats
    float* consts = win + H * WP;          // 1 float
    int*   offs   = (int*)(consts + 1);    // 2K ints (oy,ox pairs)

    geneo_win<<<dim3(8, 64), 256, 0, stream>>>(x, win, patterns, vectors, consts, offs);
    geneo_gather<<<4096, 256, 0, stream>>>(win, consts, offs, out);
}

// Round 4
// 93.508 us; speedup vs baseline: 1.2210x; 1.2210x over previous
//
#include <hip/hip_runtime.h>
#include <math.h>

#define H 2048
#define W 2048
#define K 16
#define P 15
#define WP 2052        // win pitch: W + 4 replicated guard cols (wrapped float4 reads)
#define LDSP 272       // LDS pitch: 256 tile cols + 16 halo cols

typedef float v4 __attribute__((ext_vector_type(4)));
typedef v4 uv4 __attribute__((aligned(4)));   // dword-aligned vector load

// ---- kernel 1: fused 15x15 exclusive box-sum img -> win, LDS-staged ----
// Block = 32-row x 256-col tile. 320 threads, 52 KB LDS (~3 blocks/CU).
// Block (0,0) additionally computes C and integer offsets into ws.
__global__ __launch_bounds__(320) void geneo_win(
        const float* __restrict__ img,
        float* __restrict__ win,
        const float* __restrict__ patterns,
        const float* __restrict__ vectors,
        float* __restrict__ consts,
        int* __restrict__ offs) {
    // slot s (s=1..47) holds img row r0-16+s; col-walk overwrites slot ii with
    // colsum row r0+ii (slot ii's img row is dead by then).
    __shared__ float sl[48][LDSP];   // 52,224 B
    __shared__ float psum[5];
    int t  = threadIdx.x;
    int c0 = blockIdx.x * 256;
    int r0 = blockIdx.y * 32;

    // --- consts (block (0,0) only) ---
    if (blockIdx.x == 0 && blockIdx.y == 0) {
        float ps = 0.f;
        for (int idx = t; idx < 900; idx += 320) {      // 900 v4 = 3600 floats
            v4 v = *(const v4*)&patterns[idx * 4];
            ps += (v.x + v.y) + (v.z + v.w);
        }
        #pragma unroll
        for (int d = 32; d > 0; d >>= 1) ps += __shfl_down(ps, d, 64);
        if ((t & 63) == 0) psum[t >> 6] = ps;
        if (t < 2 * K) offs[t] = (int)floorf(vectors[t]);
        __syncthreads();
        if (t == 0) {
            float total = ((psum[0] + psum[1]) + (psum[2] + psum[3])) + psum[4];
            consts[0] = (16.0f - total * (1.0f / 225.0f)) * (1.0f / 15.0f);
        }
    }

    // --- stage img rows [r0-15, r0+32) x cols [c0-16, c0+256) into LDS ---
    // 47 rows x 68 v4 = 3196 independent float4 loads, ~10 per thread (burst).
    for (int idx = t; idx < 47 * 68; idx += 320) {
        int q = idx / 68;                 // 0..46 -> img row r0-15+q -> slot q+1
        int c = idx - q * 68;             // v4 col group
        int grow = r0 - 15 + q;
        int gcol = c0 - 16 + 4 * c;
        v4 v = {0.f, 0.f, 0.f, 0.f};
        if (grow >= 0 && gcol >= 0)       // zero-pad (gcol<0 => whole v4 < 0)
            v = *(const v4*)&img[grow * W + gcol];
        *(v4*)&sl[q + 1][4 * c] = v;
    }
    __syncthreads();

    // --- vertical running sum in LDS (one column per thread, stride-1 lanes) ---
    if (t < LDSP) {
        float s = 0.f;
        #pragma unroll
        for (int q = 1; q <= 15; ++q) s += sl[q][t];     // rows r0-15..r0-1
        #pragma unroll
        for (int ii = 0; ii < 32; ++ii) {
            float sv = s;
            s += sl[ii + 16][t] - sl[ii + 1][t];         // +row r0+ii, -row r0+ii-15
            sl[ii][t] = sv;                              // colsum row r0+ii
        }
    }
    __syncthreads();

    // --- horizontal 15-tap (one output column per thread, stride-1 lanes) ---
    if (t < 256) {
        int gj = c0 + t;                  // lds col index t+16; window = t+1..t+15
        #pragma unroll 4
        for (int ii = 0; ii < 32; ++ii) {
            float s = 0.f;
            #pragma unroll
            for (int m = 1; m <= 15; ++m) s += sl[ii][t + m];
            int gi = r0 + ii;
            win[gi * WP + gj] = s;
            if (c0 == 0 && t < 4)         // guard cols 2048..2051 = cols 0..3
                win[gi * WP + 2048 + t] = s;
        }
    }
}

// ---- kernel 2: 16-way circular-shift gather-sum, XCD-banded, 8 out/thread ----
__global__ __launch_bounds__(256) void geneo_gather(
        const float* __restrict__ win,
        const float* __restrict__ consts,
        const int* __restrict__ offs,
        float* __restrict__ out) {
    __shared__ int soy[K], sox[K];
    __shared__ float sC;
    int t = threadIdx.x;
    if (t < K) { soy[t] = offs[t * 2]; sox[t] = offs[t * 2 + 1]; }
    if (t == 0) sC = consts[0];
    __syncthreads();

    // round-robin d%8 XCD assignment: XCD x gets rows [x*256, x*256+256)
    // -> its win band (~2.1 MB) fits the 4 MiB per-XCD L2
    int d   = blockIdx.x;            // 2048 blocks, one output row each
    int i   = ((d & 7) << 8) | (d >> 3);
    int j   = 4 * t;                 // cols j and j+1024 per thread

    const float S = 1.0f / 3375.0f;  // 1/(p^2 (K-1)), data-independent
    v4 acc0 = {0.f, 0.f, 0.f, 0.f};
    v4 acc1 = {0.f, 0.f, 0.f, 0.f};
    #pragma unroll
    for (int k = 0; k < K; ++k) {
        int ri = (i - soy[k]) & (H - 1);
        int rj = (j - sox[k]) & (W - 1);
        const float* row = &win[ri * WP];
        acc0 += *(const uv4*)&row[rj];
        acc1 += *(const uv4*)&row[rj ^ 1024];   // (rj+1024) mod 2048
    }
    v4 o0 = acc0 * S + sC;
    v4 o1 = acc1 * S + sC;
    *(v4*)&out[i * W + j]        = o0;
    *(v4*)&out[i * W + j + 1024] = o1;
}

extern "C" void kernel_launch(void* const* d_in, const int* in_sizes, int n_in,
                              void* d_out, int out_size, void* d_ws, size_t ws_size,
                              hipStream_t stream) {
    const float* x        = (const float*)d_in[0]; // (1,1,H,W)
    const float* patterns = (const float*)d_in[1]; // (K,P,P)
    const float* vectors  = (const float*)d_in[2]; // (K,2)
    float* out = (float*)d_out;

    float* win    = (float*)d_ws;          // H*WP floats
    float* consts = win + H * WP;          // 1 float
    int*   offs   = (int*)(consts + 1);    // 2K ints (oy,ox pairs)

    geneo_win<<<dim3(8, 64), 320, 0, stream>>>(x, win, patterns, vectors, consts, offs);
    geneo_gather<<<2048, 256, 0, stream>>>(win, consts, offs, out);
}